// Round 4
// baseline (312.947 us; speedup 1.0000x reference)
//
#include <hip/hip_runtime.h>
#include <hip/hip_cooperative_groups.h>
#include <cstdint>
#include <cstddef>

namespace cg = cooperative_groups;

#define BN 32
#define PN 1000
#define GN 24
#define NPTSN 72
#define DNN 78
#define CHN 16         // pred chunks in phase 1
#define PPC 63         // preds per chunk (16*63 >= 1000)
#define EPSF 1e-8f
#define INF __builtin_inff()

// ---- workspace layout (units of 4 bytes) ----
#define OFF_DIST  0
#define OFF_LIOU  768000
#define OFF_PX    1536000
#define OFF_PY    1568000
#define OFF_PTH   1600000
#define OFF_CLS   1632000
#define OFF_TS    1664000   // scaled target pts   [b][g][72]
#define OFF_TW    1719296   // validity weights    [b][g][72]
#define OFF_TVL   1774592   // clipped valid len   [b][g]
#define OFF_TNV   1775360   // unclipped valid len [b][g]
#define OFF_TGX   1776128
#define OFF_TGY   1776896
#define OFF_TGTH  1777664
#define OFF_GM    1778432   // gt mask (int)       [b][g]
#define OFF_NG    1779200   // num masked (int)    [b]
#define OFF_PART  1779232   // partial maxima      [b][16][3]
#define OFF_CNT   1780768   // match count (int)   [b][p]
#define OFF_SELG  1812768   // unique selector g   [b][p]
#define OFF_BEST  1844768   // u64 (ordcost<<32|g) [b][p]  (even -> 8B aligned)

// ---------- helpers ----------
__device__ __forceinline__ unsigned ordf(float f) {
  unsigned u = __float_as_uint(f);
  return (u & 0x80000000u) ? ~u : (u | 0x80000000u);
}
__device__ __forceinline__ float unordf(unsigned u) {
  return __uint_as_float((u & 0x80000000u) ? (u ^ 0x80000000u) : ~u);
}
__device__ __forceinline__ unsigned long long shfl_xor_u64(unsigned long long v, int m) {
  int lo = __shfl_xor((int)(unsigned)v, m);
  int hi = __shfl_xor((int)(unsigned)(v >> 32), m);
  return (((unsigned long long)(unsigned)hi) << 32) | (unsigned)lo;
}

// masks may arrive as int32, uint8, or float32. mask[b][0] is always true
// (num_gt >= 1), which makes the layouts distinguishable.
__device__ int detect_mask_layout(const void* masks, int* sflag) {
  const unsigned* mw = (const unsigned*)masks;
  if (mw[0] == 0x3f800000u) return 2;   // float32 1.0f
  if (threadIdx.x == 0) *sflag = 0;
  __syncthreads();
  const unsigned char* mb = (const unsigned char*)masks;
  int local = 0;
  for (int i = threadIdx.x; i < BN * GN; i += blockDim.x)
    if ((i & 3) != 0 && mb[i] != 0) local = 1;
  if (local) atomicOr(sflag, 1);
  __syncthreads();
  return (*sflag) ? 1 : 0;
}
__device__ __forceinline__ int mask_val(const void* masks, int layout, int idx) {
  if (layout == 2) return ((const float*)masks)[idx] != 0.0f;
  if (layout == 1) return ((const unsigned char*)masks)[idx] != 0;
  return ((const int*)masks)[idx] != 0;
}

// ---------- single fused cooperative kernel ----------
__global__ __launch_bounds__(256, 1) void clr_all(
    const float* __restrict__ preds, const float* __restrict__ targets,
    const void* __restrict__ masks, const int* __restrict__ imw,
    const int* __restrict__ imh, float* __restrict__ ws, int* __restrict__ out)
{
  cg::grid_group grid = cg::this_grid();
  const int blk = blockIdx.x;
  const int tid = threadIdx.x;
  const int lane = tid & 63;
  int* wsi = (int*)ws;
  unsigned long long* bst = (unsigned long long*)(ws + OFF_BEST);
  const float wf = (float)imw[0];
  const float wm1 = wf - 1.0f, hm1 = (float)imh[0] - 1.0f;

  __shared__ float sts[GN * NPTSN];
  __shared__ float stw[GN * NPTSN];
  __shared__ int sgm[GN];
  __shared__ int sflag;
  __shared__ float red[4][3];
  __shared__ unsigned long long ctop[4][4], ltop[4][4];

  // ======== phase 0: zone init (all blocks) + per-batch prep (blocks 0..31) ========
  {
    int i = blk * 256 + tid;
    if (i < BN * PN) {
      wsi[OFF_CNT + i] = 0;
      wsi[OFF_SELG + i] = 0x7fffffff;
      bst[i] = ~0ull;
    }
  }
  if (blk < BN) {
    const int b = blk;
    const int mlay = detect_mask_layout(masks, &sflag);
    for (int idx = tid; idx < GN * NPTSN; idx += 256) {
      int g = idx / NPTSN, j = idx - g * NPTSN;
      float t = targets[(size_t)(b * GN + g) * DNN + 6 + j] * wm1;
      sts[idx] = t;
      stw[idx] = (t >= 0.0f && t < wf) ? 1.0f : 0.0f;
    }
    __syncthreads();
    if (tid < GN) {
      float cnt = 0.0f;
      for (int j = 0; j < NPTSN; j++) cnt += stw[tid * NPTSN + j];
      ws[OFF_TNV + b * GN + tid] = cnt;               // unclipped (liou)
      ws[OFF_TVL + b * GN + tid] = fmaxf(cnt, 1.0f);  // clipped (dist)
      const float* tr = targets + (size_t)(b * GN + tid) * DNN;
      ws[OFF_TGX  + b * GN + tid] = tr[2] * hm1;
      ws[OFF_TGY  + b * GN + tid] = tr[3] * wm1;
      ws[OFF_TGTH + b * GN + tid] = tr[4] * 180.0f;
      int m = mask_val(masks, mlay, b * GN + tid);
      sgm[tid] = m;
      wsi[OFF_GM + b * GN + tid] = m;
    }
    __syncthreads();
    if (tid == 0) {
      int n = 0;
      for (int g = 0; g < GN; g++) n += sgm[g];
      wsi[OFF_NG + b] = n;
    }
    for (int idx = tid; idx < GN * NPTSN; idx += 256) {
      ws[OFF_TS + b * GN * NPTSN + idx] = sts[idx];
      ws[OFF_TW + b * GN * NPTSN + idx] = stw[idx];
    }
  }
  __threadfence();
  grid.sync();
  __threadfence();

  // ======== phase 1: heavy (p,g) loop — 2 chunk-tasks per block ========
  const float* cws = (const float*)ws;
  const int gq = __builtin_amdgcn_readfirstlane(tid >> 6);  // uniform wave id
  for (int t2 = 0; t2 < 2; t2++) {
    const int task = blk * 2 + t2;
    const int c = task & 15, b = task >> 4;
    const int p = c * PPC + lane;
    const bool active = (lane < PPC) && (p < PN);
    const int ng = ((const int*)cws)[OFF_NG + b];   // mask is a prefix (arange<num_gt)

    float pp[NPTSN];
    float ppx = 0.f, ppy = 0.f, ppth = 0.f;
    if (active) {
      const float* row = preds + (size_t)(b * PN + p) * DNN;
      const float2* r2 = (const float2*)row;     // 8B-aligned (78 floats/row)
      float2 c23 = r2[1], c45 = r2[2];
      ppx = c23.x * hm1; ppy = c23.y * wm1; ppth = c45.x * 180.0f;
      #pragma unroll
      for (int j = 0; j < NPTSN / 2; j++) {
        float2 v = r2[3 + j];
        pp[2 * j]     = v.x * wm1;
        pp[2 * j + 1] = v.y * wm1;
      }
      if (gq == 0) {
        float2 c01 = r2[0];
        float m = fmaxf(c01.x, c01.y);
        float e0 = expf(c01.x - m), e1 = expf(c01.y - m);
        float p1 = fmaxf(e1 / (e0 + e1), EPSF);
        ws[OFF_PX  + b * PN + p] = ppx;
        ws[OFF_PY  + b * PN + p] = ppy;
        ws[OFF_PTH + b * PN + p] = ppth;
        ws[OFF_CLS + b * PN + p] = -logf(p1);
      }
    } else {
      #pragma unroll
      for (int j = 0; j < NPTSN; j++) pp[j] = 0.0f;
    }

    float mxd = -INF, mxs = -INF, mxt = -INF;
    for (int i = 0; i < 6; i++) {
      const int g = gq * 6 + i;             // wave-uniform
      if (g >= ng) break;                   // unmasked suffix: never read downstream
      const int bg = b * GN + g;
      const float* ts = cws + OFF_TS + (size_t)bg * NPTSN;   // scalar loads
      const float* tw = cws + OFF_TW + (size_t)bg * NPTSN;   // scalar loads
      float S0 = 0.f, S1 = 0.f, S2 = 0.f, S3 = 0.f;
      #pragma unroll
      for (int j = 0; j < NPTSN; j += 4) {
        S0 += tw[j]     * fabsf(pp[j]     - ts[j]);
        S1 += tw[j + 1] * fabsf(pp[j + 1] - ts[j + 1]);
        S2 += tw[j + 2] * fabsf(pp[j + 2] - ts[j + 2]);
        S3 += tw[j + 3] * fabsf(pp[j + 3] - ts[j + 3]);
      }
      float S = (S0 + S1) + (S2 + S3);
      const float VL = cws[OFF_TVL + bg];
      const float NV = cws[OFF_TNV + bg];
      float dist = S / VL;
      float liou = (30.0f * NV - S) / (30.0f * NV + S + 1e-9f);
      float dx = ppx - cws[OFF_TGX + bg], dy = ppy - cws[OFF_TGY + bg];
      float sd = sqrtf(dx * dx + dy * dy);
      float td = fabsf(ppth - cws[OFF_TGTH + bg]);
      if (active) {
        size_t o = (size_t)bg * PN + p;
        ws[OFF_DIST + o] = dist;
        ws[OFF_LIOU + o] = liou;
        mxd = fmaxf(mxd, dist);
        mxs = fmaxf(mxs, sd);
        mxt = fmaxf(mxt, td);
      }
    }

    #pragma unroll
    for (int off = 32; off; off >>= 1) {
      mxd = fmaxf(mxd, __shfl_xor(mxd, off));
      mxs = fmaxf(mxs, __shfl_xor(mxs, off));
      mxt = fmaxf(mxt, __shfl_xor(mxt, off));
    }
    if (lane == 0) { red[gq][0] = mxd; red[gq][1] = mxs; red[gq][2] = mxt; }
    __syncthreads();
    if (tid == 0) {
      float a = red[0][0], s = red[0][1], t = red[0][2];
      for (int i = 1; i < 4; i++) {
        a = fmaxf(a, red[i][0]);
        s = fmaxf(s, red[i][1]);
        t = fmaxf(t, red[i][2]);
      }
      ws[OFF_PART + (b * CHN + c) * 3 + 0] = a;
      ws[OFF_PART + (b * CHN + c) * 3 + 1] = s;
      ws[OFF_PART + (b * CHN + c) * 3 + 2] = t;
    }
    __syncthreads();   // protect red[] reuse across tasks
  }
  __threadfence();
  grid.sync();
  __threadfence();

  // ======== phase 2: per-(b,g) cost top-4 / liou top-4 + scatter atomics — 3 tasks ========
  const int wv = tid >> 6;
  for (int t3 = 0; t3 < 3; t3++) {
    const int task = blk * 3 + t3;
    const int g = task % GN, b = task / GN;
    const int bg = b * GN + g;
    if (((const int*)cws)[OFF_GM + bg]) {   // block-uniform branch
      float Md = -INF, Ms = -INF, Mt = -INF;
      for (int c2 = 0; c2 < CHN; c2++) {
        Md = fmaxf(Md, cws[OFF_PART + (b * CHN + c2) * 3 + 0]);
        Ms = fmaxf(Ms, cws[OFF_PART + (b * CHN + c2) * 3 + 1]);
        Mt = fmaxf(Mt, cws[OFF_PART + (b * CHN + c2) * 3 + 2]);
      }
      const float tx = cws[OFF_TGX + bg], ty = cws[OFF_TGY + bg], tth = cws[OFF_TGTH + bg];
      const size_t dbase = (size_t)bg * PN;

      unsigned long long ck[4], lk[4];
      #pragma unroll
      for (int i = 0; i < 4; i++) {
        int p = tid + i * 256;
        unsigned long long kc = ~0ull, kl = ~0ull;
        if (p < PN) {
          float dist = cws[OFF_DIST + dbase + p];
          float liou = cws[OFF_LIOU + dbase + p];
          float px  = cws[OFF_PX  + b * PN + p];
          float py  = cws[OFF_PY  + b * PN + p];
          float pth = cws[OFF_PTH + b * PN + p];
          float cls = cws[OFF_CLS + b * PN + p];
          float dsc = (1.0f - dist / (Md + EPSF)) + 0.01f;
          float dx = px - tx, dy = py - ty;
          float xsc = (1.0f - sqrtf(dx * dx + dy * dy) / (Ms + EPSF)) + 0.01f;
          float tsc = (1.0f - fabsf(pth - tth) / (Mt + EPSF)) + 0.01f;
          float r = (dsc * xsc) * tsc;
          float cost = -(r * r) * 3.0f + cls;
          unsigned oc = ordf(cost);
          kc = (((unsigned long long)oc) << 32) | (unsigned)p;
          kl = (((unsigned long long)(unsigned)(~ordf(liou))) << 32) | (unsigned)p;
          // argmin-over-g for multi-match resolve (first-occurrence tie-break on g)
          atomicMin(&bst[b * PN + p], (((unsigned long long)oc) << 32) | (unsigned)g);
        }
        ck[i] = kc; lk[i] = kl;
      }

      #pragma unroll
      for (int pass = 0; pass < 4; pass++) {
        unsigned long long m = ck[0];
        #pragma unroll
        for (int i = 1; i < 4; i++) m = (ck[i] < m) ? ck[i] : m;
        #pragma unroll
        for (int off = 32; off; off >>= 1) {
          unsigned long long o = shfl_xor_u64(m, off);
          m = (o < m) ? o : m;
        }
        #pragma unroll
        for (int i = 0; i < 4; i++) if (ck[i] == m) ck[i] = ~0ull;
        if (lane == 0) ctop[wv][pass] = m;
      }
      #pragma unroll
      for (int pass = 0; pass < 4; pass++) {
        unsigned long long m = lk[0];
        #pragma unroll
        for (int i = 1; i < 4; i++) m = (lk[i] < m) ? lk[i] : m;
        #pragma unroll
        for (int off = 32; off; off >>= 1) {
          unsigned long long o = shfl_xor_u64(m, off);
          m = (o < m) ? o : m;
        }
        #pragma unroll
        for (int i = 0; i < 4; i++) if (lk[i] == m) lk[i] = ~0ull;
        if (lane == 0) ltop[wv][pass] = m;
      }
      __syncthreads();

      if (tid == 0) {
        unsigned long long c4[4] = {~0ull, ~0ull, ~0ull, ~0ull};
        unsigned long long l4[4] = {~0ull, ~0ull, ~0ull, ~0ull};
        for (int i = 0; i < 16; i++) {
          unsigned long long v = ctop[i >> 2][i & 3];
          for (int j = 0; j < 4; j++)
            if (v < c4[j]) { unsigned long long t = c4[j]; c4[j] = v; v = t; }
          v = ltop[i >> 2][i & 3];
          for (int j = 0; j < 4; j++)
            if (v < l4[j]) { unsigned long long t = l4[j]; l4[j] = v; v = t; }
        }
        // l4 ascending keys == liou descending values; sum in that order like top_k
        float s = 0.0f;
        for (int j = 0; j < 4; j++) s += unordf(~(unsigned)(l4[j] >> 32));
        int k = (int)s;                 // trunc toward zero == astype(int32)
        if (k < 1) k = 1;
        if (k > 4) k = 4;
        for (int j = 0; j < k; j++) {
          int cand = (int)(unsigned)(c4[j] & 0xffffffffu);
          atomicAdd(&wsi[OFF_CNT + b * PN + cand], 1);
          atomicMin(&wsi[OFF_SELG + b * PN + cand], g);
        }
      }
      __syncthreads();   // protect ctop/ltop reuse across tasks
    }
  }
  __threadfence();
  grid.sync();
  __threadfence();

  // ======== phase 3: streaming finalize ========
  {
    int i = blk * 256 + tid;
    if (i < BN * PN) {
      int cnt = wsi[OFF_CNT + i];
      int assigned = cnt > 0 ? 1 : 0;
      int matched = -1;
      if (cnt == 1) matched = wsi[OFF_SELG + i];
      else if (cnt > 1) matched = (int)(unsigned)(bst[i] & 0xffffffffull);
      out[i] = assigned;
      out[BN * PN + i] = matched;
    }
  }
}

extern "C" void kernel_launch(void* const* d_in, const int* in_sizes, int n_in,
                              void* d_out, int out_size, void* d_ws, size_t ws_size,
                              hipStream_t stream) {
  const float* preds   = (const float*)d_in[0];
  const float* targets = (const float*)d_in[1];
  const void*  masks   = (const void*)d_in[2];
  const int*   imw     = (const int*)d_in[3];
  const int*   imh     = (const int*)d_in[4];
  float* ws = (float*)d_ws;
  int*   out = (int*)d_out;

  void* args[] = { (void*)&preds, (void*)&targets, (void*)&masks,
                   (void*)&imw, (void*)&imh, (void*)&ws, (void*)&out };
  hipLaunchCooperativeKernel(reinterpret_cast<void*>(clr_all),
                             dim3(256), dim3(256), args, 0, stream);
}

// Round 5
// 95.503 us; speedup vs baseline: 3.2768x; 3.2768x over previous
//
#include <hip/hip_runtime.h>
#include <cstdint>
#include <cstddef>

#define BN 32
#define PN 1000
#define GN 24
#define NPTSN 72
#define DNN 78
#define CHN 16         // pred chunks in K1
#define PPC 63         // preds per chunk (16*63 >= 1000)
#define EPSF 1e-8f
#define INF __builtin_inff()

// ---- workspace layout (units of 4 bytes) ----
#define OFF_DIST  0
#define OFF_LIOU  768000
#define OFF_PX    1536000
#define OFF_PY    1568000
#define OFF_PTH   1600000
#define OFF_CLS   1632000
#define OFF_PART  1664000   // partial maxima [b][16][3]
#define OFF_CNT   1665536   // match count (int)   [b][p]
#define OFF_SELG  1697536   // unique selector g   [b][p]
#define OFF_BEST  1729536   // u64 (ordcost<<32|g) [b][p]  (even -> 8B aligned)
// total ~1.79M floats = 7.2 MB (ws is 256 MB)

// ---------- helpers ----------
__device__ __forceinline__ unsigned ordf(float f) {
  unsigned u = __float_as_uint(f);
  return (u & 0x80000000u) ? ~u : (u | 0x80000000u);
}
__device__ __forceinline__ float unordf(unsigned u) {
  return __uint_as_float((u & 0x80000000u) ? (u ^ 0x80000000u) : ~u);
}
__device__ __forceinline__ unsigned long long shfl_xor_u64(unsigned long long v, int m) {
  int lo = __shfl_xor((int)(unsigned)v, m);
  int hi = __shfl_xor((int)(unsigned)(v >> 32), m);
  return (((unsigned long long)(unsigned)hi) << 32) | (unsigned)lo;
}

// masks may arrive as int32, uint8, or float32. mask[b][0] is always true
// (num_gt >= 1), which makes the layouts distinguishable.
// Must be called by ALL threads of the block (contains __syncthreads).
__device__ int detect_mask_layout(const void* masks, int* sflag) {
  const unsigned* mw = (const unsigned*)masks;
  if (mw[0] == 0x3f800000u) return 2;   // float32 1.0f
  if (threadIdx.x == 0) *sflag = 0;
  __syncthreads();
  const unsigned char* mb = (const unsigned char*)masks;
  int local = 0;
  for (int i = threadIdx.x; i < BN * GN; i += blockDim.x)
    if ((i & 3) != 0 && mb[i] != 0) local = 1;
  if (local) atomicOr(sflag, 1);
  __syncthreads();
  return (*sflag) ? 1 : 0;
}
__device__ __forceinline__ int mask_val(const void* masks, int layout, int idx) {
  if (layout == 2) return ((const float*)masks)[idx] != 0.0f;
  if (layout == 1) return ((const unsigned char*)masks)[idx] != 0;
  return ((const int*)masks)[idx] != 0;
}

// ---------- K1: zone init + per-block target prep (LDS) + heavy (p,g) loop ----------
__global__ __launch_bounds__(256) void clr_k1(
    const float* __restrict__ preds, const float* __restrict__ targets,
    const void* __restrict__ masks, const int* __restrict__ imw,
    const int* __restrict__ imh, float* __restrict__ ws)
{
  const int b = blockIdx.y, c = blockIdx.x;
  const int tid = threadIdx.x;
  const int lane = tid & 63;
  const int gq = __builtin_amdgcn_readfirstlane(tid >> 6);  // uniform wave id
  const float wf = (float)imw[0];
  const float wm1 = wf - 1.0f, hm1 = (float)imh[0] - 1.0f;

  // ---- zone init (nothing reads these until K2a, a later kernel) ----
  {
    int gid = (b * CHN + c) * 256 + tid;
    if (gid < BN * PN) {
      int* wsi = (int*)ws;
      wsi[OFF_CNT + gid] = 0;
      wsi[OFF_SELG + gid] = 0x7fffffff;
      ((unsigned long long*)(ws + OFF_BEST))[gid] = ~0ull;
    }
  }

  // ---- per-block target prep into LDS ----
  __shared__ __align__(16) float sts[GN * NPTSN];
  __shared__ __align__(16) float stw[GN * NPTSN];
  __shared__ float svl[GN], snv[GN], sgx[GN], sgy[GN], sgth[GN];
  __shared__ int sgm[GN];
  __shared__ int sng;
  __shared__ int sflag;
  __shared__ float red[4][3];

  const int mlay = detect_mask_layout(masks, &sflag);

  for (int idx = tid; idx < GN * NPTSN; idx += 256) {
    int g = idx / NPTSN, j = idx - g * NPTSN;
    float t = targets[(size_t)(b * GN + g) * DNN + 6 + j] * wm1;
    sts[idx] = t;
    stw[idx] = (t >= 0.0f && t < wf) ? 1.0f : 0.0f;
  }
  __syncthreads();
  if (tid < GN) {
    float cnt = 0.0f;
    for (int j = 0; j < NPTSN; j++) cnt += stw[tid * NPTSN + j];
    snv[tid] = cnt;               // unclipped (liou)
    svl[tid] = fmaxf(cnt, 1.0f);  // clipped (dist)
    const float* tr = targets + (size_t)(b * GN + tid) * DNN;
    sgx[tid]  = tr[2] * hm1;
    sgy[tid]  = tr[3] * wm1;
    sgth[tid] = tr[4] * 180.0f;
    sgm[tid] = mask_val(masks, mlay, b * GN + tid);
  }
  __syncthreads();
  if (tid == 0) {
    int n = 0;
    for (int g = 0; g < GN; g++) n += sgm[g];
    sng = n;   // mask is a prefix (arange < num_gt)
  }
  __syncthreads();
  const int ng = sng;

  // ---- per-pred load ----
  const int p = c * PPC + lane;
  const bool active = (lane < PPC) && (p < PN);
  float pp[NPTSN];
  float ppx = 0.f, ppy = 0.f, ppth = 0.f;
  if (active) {
    const float* row = preds + (size_t)(b * PN + p) * DNN;
    const float2* r2 = (const float2*)row;     // 8B-aligned (78 floats/row)
    float2 c23 = r2[1], c45 = r2[2];
    ppx = c23.x * hm1; ppy = c23.y * wm1; ppth = c45.x * 180.0f;
    #pragma unroll
    for (int j = 0; j < NPTSN / 2; j++) {
      float2 v = r2[3 + j];
      pp[2 * j]     = v.x * wm1;
      pp[2 * j + 1] = v.y * wm1;
    }
    if (gq == 0) {
      float2 c01 = r2[0];
      float m = fmaxf(c01.x, c01.y);
      float e0 = expf(c01.x - m), e1 = expf(c01.y - m);
      float p1 = fmaxf(e1 / (e0 + e1), EPSF);
      ws[OFF_PX  + b * PN + p] = ppx;
      ws[OFF_PY  + b * PN + p] = ppy;
      ws[OFF_PTH + b * PN + p] = ppth;
      ws[OFF_CLS + b * PN + p] = -logf(p1);
    }
  } else {
    #pragma unroll
    for (int j = 0; j < NPTSN; j++) pp[j] = 0.0f;
  }

  // ---- heavy loop: g interleaved across waves for balance (g = gq + 4i) ----
  float mxd = -INF, mxs = -INF, mxt = -INF;
  for (int i = 0; i < 6; i++) {
    const int g = gq + 4 * i;             // wave-uniform, balanced over masked prefix
    if (g >= ng) break;
    const float4* t4 = (const float4*)&sts[g * NPTSN];  // broadcast ds_read_b128
    const float4* w4 = (const float4*)&stw[g * NPTSN];
    float S0 = 0.f, S1 = 0.f, S2 = 0.f, S3 = 0.f;
    #pragma unroll
    for (int jj = 0; jj < NPTSN / 4; jj++) {
      float4 t = t4[jj], w = w4[jj];
      S0 += w.x * fabsf(pp[4 * jj + 0] - t.x);
      S1 += w.y * fabsf(pp[4 * jj + 1] - t.y);
      S2 += w.z * fabsf(pp[4 * jj + 2] - t.z);
      S3 += w.w * fabsf(pp[4 * jj + 3] - t.w);
    }
    float S = (S0 + S1) + (S2 + S3);
    const float VL = svl[g], NV = snv[g];
    float dist = S / VL;
    float liou = (30.0f * NV - S) / (30.0f * NV + S + 1e-9f);
    float dx = ppx - sgx[g], dy = ppy - sgy[g];
    float sd = sqrtf(dx * dx + dy * dy);
    float td = fabsf(ppth - sgth[g]);
    if (active) {
      size_t o = (size_t)(b * GN + g) * PN + p;
      ws[OFF_DIST + o] = dist;
      ws[OFF_LIOU + o] = liou;
      mxd = fmaxf(mxd, dist);
      mxs = fmaxf(mxs, sd);
      mxt = fmaxf(mxt, td);
    }
  }

  #pragma unroll
  for (int off = 32; off; off >>= 1) {
    mxd = fmaxf(mxd, __shfl_xor(mxd, off));
    mxs = fmaxf(mxs, __shfl_xor(mxs, off));
    mxt = fmaxf(mxt, __shfl_xor(mxt, off));
  }
  if (lane == 0) { red[gq][0] = mxd; red[gq][1] = mxs; red[gq][2] = mxt; }
  __syncthreads();
  if (tid == 0) {
    float a = red[0][0], s = red[0][1], t = red[0][2];
    for (int i = 1; i < 4; i++) {
      a = fmaxf(a, red[i][0]);
      s = fmaxf(s, red[i][1]);
      t = fmaxf(t, red[i][2]);
    }
    ws[OFF_PART + (b * CHN + c) * 3 + 0] = a;
    ws[OFF_PART + (b * CHN + c) * 3 + 1] = s;
    ws[OFF_PART + (b * CHN + c) * 3 + 2] = t;
  }
}

// ---------- K2a: per (b,g): cost, top-4 cost / top-4 liou, ks; scatter atomics ----------
__global__ __launch_bounds__(256) void clr_k2a(
    const float* __restrict__ targets, const void* __restrict__ masks,
    const int* __restrict__ imw, const int* __restrict__ imh,
    const float* __restrict__ cws, float* __restrict__ ws)
{
  const int g = blockIdx.x, b = blockIdx.y;
  const int bg = b * GN + g;
  __shared__ int sflag;
  const int mlay = detect_mask_layout(masks, &sflag);   // all threads (has barrier)
  if (!mask_val(masks, mlay, bg)) return;   // unmasked column: contributes nothing

  const int tid = threadIdx.x;
  const int lane = tid & 63;
  const int wv = tid >> 6;
  const float hm1 = (float)imh[0] - 1.0f;
  const float wm1 = (float)imw[0] - 1.0f;

  float Md = -INF, Ms = -INF, Mt = -INF;
  for (int c2 = 0; c2 < CHN; c2++) {
    Md = fmaxf(Md, cws[OFF_PART + (b * CHN + c2) * 3 + 0]);
    Ms = fmaxf(Ms, cws[OFF_PART + (b * CHN + c2) * 3 + 1]);
    Mt = fmaxf(Mt, cws[OFF_PART + (b * CHN + c2) * 3 + 2]);
  }
  const float* tr = targets + (size_t)bg * DNN;
  const float tx = tr[2] * hm1, ty = tr[3] * wm1, tth = tr[4] * 180.0f;
  const size_t dbase = (size_t)bg * PN;
  unsigned long long* bst = (unsigned long long*)(ws + OFF_BEST);
  int* wsi = (int*)ws;

  unsigned long long ck[4], lk[4];
  #pragma unroll
  for (int i = 0; i < 4; i++) {
    int p = tid + i * 256;
    unsigned long long kc = ~0ull, kl = ~0ull;
    if (p < PN) {
      float dist = cws[OFF_DIST + dbase + p];
      float liou = cws[OFF_LIOU + dbase + p];
      float px  = cws[OFF_PX  + b * PN + p];
      float py  = cws[OFF_PY  + b * PN + p];
      float pth = cws[OFF_PTH + b * PN + p];
      float cls = cws[OFF_CLS + b * PN + p];
      float dsc = (1.0f - dist / (Md + EPSF)) + 0.01f;
      float dx = px - tx, dy = py - ty;
      float xsc = (1.0f - sqrtf(dx * dx + dy * dy) / (Ms + EPSF)) + 0.01f;
      float tsc = (1.0f - fabsf(pth - tth) / (Mt + EPSF)) + 0.01f;
      float r = (dsc * xsc) * tsc;
      float cost = -(r * r) * 3.0f + cls;
      unsigned oc = ordf(cost);
      kc = (((unsigned long long)oc) << 32) | (unsigned)p;
      kl = (((unsigned long long)(unsigned)(~ordf(liou))) << 32) | (unsigned)p;
      // argmin-over-g for multi-match resolve (first-occurrence tie-break on g)
      atomicMin(&bst[b * PN + p], (((unsigned long long)oc) << 32) | (unsigned)g);
    }
    ck[i] = kc; lk[i] = kl;
  }

  __shared__ unsigned long long ctop[4][4], ltop[4][4];
  #pragma unroll
  for (int pass = 0; pass < 4; pass++) {
    unsigned long long m = ck[0];
    #pragma unroll
    for (int i = 1; i < 4; i++) m = (ck[i] < m) ? ck[i] : m;
    #pragma unroll
    for (int off = 32; off; off >>= 1) {
      unsigned long long o = shfl_xor_u64(m, off);
      m = (o < m) ? o : m;
    }
    #pragma unroll
    for (int i = 0; i < 4; i++) if (ck[i] == m) ck[i] = ~0ull;
    if (lane == 0) ctop[wv][pass] = m;
  }
  #pragma unroll
  for (int pass = 0; pass < 4; pass++) {
    unsigned long long m = lk[0];
    #pragma unroll
    for (int i = 1; i < 4; i++) m = (lk[i] < m) ? lk[i] : m;
    #pragma unroll
    for (int off = 32; off; off >>= 1) {
      unsigned long long o = shfl_xor_u64(m, off);
      m = (o < m) ? o : m;
    }
    #pragma unroll
    for (int i = 0; i < 4; i++) if (lk[i] == m) lk[i] = ~0ull;
    if (lane == 0) ltop[wv][pass] = m;
  }
  __syncthreads();

  if (tid == 0) {
    unsigned long long c4[4] = {~0ull, ~0ull, ~0ull, ~0ull};
    unsigned long long l4[4] = {~0ull, ~0ull, ~0ull, ~0ull};
    for (int i = 0; i < 16; i++) {
      unsigned long long v = ctop[i >> 2][i & 3];
      for (int j = 0; j < 4; j++)
        if (v < c4[j]) { unsigned long long t = c4[j]; c4[j] = v; v = t; }
      v = ltop[i >> 2][i & 3];
      for (int j = 0; j < 4; j++)
        if (v < l4[j]) { unsigned long long t = l4[j]; l4[j] = v; v = t; }
    }
    // l4 ascending keys == liou descending values; sum in that order like top_k
    float s = 0.0f;
    for (int j = 0; j < 4; j++) s += unordf(~(unsigned)(l4[j] >> 32));
    int k = (int)s;                 // trunc toward zero == astype(int32)
    if (k < 1) k = 1;
    if (k > 4) k = 4;
    for (int j = 0; j < k; j++) {
      int cand = (int)(unsigned)(c4[j] & 0xffffffffu);
      atomicAdd(&wsi[OFF_CNT + b * PN + cand], 1);
      atomicMin(&wsi[OFF_SELG + b * PN + cand], g);
    }
  }
}

// ---------- K2b: streaming finalize ----------
__global__ __launch_bounds__(256) void clr_k2b(
    const float* __restrict__ cws, int* __restrict__ out)
{
  const int i = blockIdx.x * 256 + threadIdx.x;
  if (i >= BN * PN) return;
  const int* wsi = (const int*)cws;
  const unsigned long long* bst = (const unsigned long long*)(cws + OFF_BEST);
  int cnt = wsi[OFF_CNT + i];
  int assigned = cnt > 0 ? 1 : 0;
  int matched = -1;
  if (cnt == 1) matched = wsi[OFF_SELG + i];
  else if (cnt > 1) matched = (int)(unsigned)(bst[i] & 0xffffffffull);
  out[i] = assigned;
  out[BN * PN + i] = matched;
}

extern "C" void kernel_launch(void* const* d_in, const int* in_sizes, int n_in,
                              void* d_out, int out_size, void* d_ws, size_t ws_size,
                              hipStream_t stream) {
  const float* preds   = (const float*)d_in[0];
  const float* targets = (const float*)d_in[1];
  const void*  masks   = (const void*)d_in[2];
  const int*   imw     = (const int*)d_in[3];
  const int*   imh     = (const int*)d_in[4];
  float* ws = (float*)d_ws;
  int*   out = (int*)d_out;

  hipLaunchKernelGGL(clr_k1, dim3(CHN, BN), dim3(256), 0, stream,
                     preds, targets, masks, imw, imh, ws);
  hipLaunchKernelGGL(clr_k2a, dim3(GN, BN), dim3(256), 0, stream,
                     targets, masks, imw, imh, (const float*)d_ws, ws);
  hipLaunchKernelGGL(clr_k2b, dim3((BN * PN + 255) / 256), dim3(256), 0, stream,
                     (const float*)d_ws, out);
}